// Round 8
// baseline (175.744 us; speedup 1.0000x reference)
//
#include <hip/hip_runtime.h>
#include <hip/hip_bf16.h>

// SparseMHA, fixed out-degree CSR graph attention. fp32 in/out.
// r16 -> r17:
//  * Budget (measured via r15's controlled perturbation): total = attn 54.4
//    + qkv ~44 + ~74us fixed harness overhead. attn is at the compulsory
//    random-gather byte wall (4 falsifications) — untouched.
//  * qkv: staging mechanism (DMA vs VALU-split), drain count (6 vs 3), and
//    prep fusion all left qkv at ~43-45us -> the remaining common factor is
//    the SERIAL 3-projection loop per block. Now unrolled ACROSS THE GRID:
//    block (p, b) computes one projection for one 128-row tile. Per-block
//    critical path 3x shorter (3 syncs, one stage+MFMA+epilogue), 1173
//    blocks smooth the makespan over 512 co-resident slots, VGPR drops.
//    h read 3x (L2-hit after first touch) and A-split recomputed 3x — cheap.
//    Numerics bit-identical (same op order per projection).
//    If this is neutral too, qkv is at a system floor -> roofline.

typedef unsigned short ushort_t;
typedef unsigned int uint32;
typedef short short8 __attribute__((ext_vector_type(8)));
typedef short short4v __attribute__((ext_vector_type(4)));
typedef float f32x4 __attribute__((ext_vector_type(4)));
typedef float f32x2 __attribute__((ext_vector_type(2)));

#define HID 128
#define DEG 16
#define OSTRIDE_LDS 132   // ushort row stride in LDS repack (bank-conflict-free)

__device__ __forceinline__ float bf2f(ushort_t u) {
  uint32 x = ((uint32)u) << 16;
  return __builtin_bit_cast(float, x);
}
__device__ __forceinline__ ushort_t f2bf(float f) {
  uint32 u = __builtin_bit_cast(uint32, f);
  u += 0x7fffu + ((u >> 16) & 1u);   // RNE
  return (ushort_t)(u >> 16);
}

// Packed split of 2 fp32 -> packed bf16 hi pair + lo pair (RNE, v_cvt_pk path).
__device__ __forceinline__ void split2(float x, float y, uint32& hi, uint32& lo) {
  __hip_bfloat162 h2 = __float22bfloat162_rn(float2{x, y});
  __builtin_memcpy(&hi, &h2, 4);
  float hx = __builtin_bit_cast(float, hi << 16);
  float hy = __builtin_bit_cast(float, hi & 0xffff0000u);
  __hip_bfloat162 l2 = __float22bfloat162_rn(float2{x - hx, y - hy});
  __builtin_memcpy(&lo, &l2, 4);
}

__device__ __forceinline__ void split8v(float4 a, float4 b, short8& hi, short8& lo) {
  uint32* hu = (uint32*)&hi;
  uint32* lu = (uint32*)&lo;
  split2(a.x, a.y, hu[0], lu[0]);
  split2(a.z, a.w, hu[1], lu[1]);
  split2(b.x, b.y, hu[2], lu[2]);
  split2(b.z, b.w, hu[3], lu[3]);
}

__device__ __forceinline__ void split8p(const float* __restrict__ p, short8& hi, short8& lo) {
  float4 a = *(const float4*)p;
  float4 b = *(const float4*)(p + 4);
  split8v(a, b, hi, lo);
}

// ---------------- Phase 1: fused W-split + projection, grid-unrolled --------
// Block (p, b): projection p (0=q,1=k,2=v) for rows [b*128, b*128+128).
// 4 waves x 32 rows. Stage: each wave loads its 8 W-fragments as fp32
// (L2-hit), splits to bf16 hi/lo in VALU, ds_writes hi[0,32K) lo[32K,64K);
// ONE sync; 192 MFMA/wave; sync; repack into dead B region; stores.
// B fragment slot j = t*4+kt (1KB each): lane l holds bytes j*1024 + l*16.
__global__ __launch_bounds__(256) void qkv_fused_kernel(
    const float* __restrict__ h,
    const float* __restrict__ Wq, const float* __restrict__ bq,
    const float* __restrict__ Wk, const float* __restrict__ bk,
    const float* __restrict__ Wv, const float* __restrict__ bv,
    ushort_t* __restrict__ qs, ushort_t* __restrict__ kvt,
    int n, int nb) {
  __shared__ __align__(16) char lds_b[64 * 1024];   // hi | lo fragments; front
                                                    // 33.8KB reused as repack
  const int p = blockIdx.x / nb;                    // projection
  const int b = blockIdx.x - p * nb;                // row tile
  const int wave = threadIdx.x >> 6;
  const int l = threadIdx.x & 63;
  const int lm = l & 15;
  const int lq = l >> 4;
  const int m0 = b * 128 + wave * 32;

  const float* __restrict__ W = (p == 0) ? Wq : (p == 1) ? Wk : Wv;
  const float* __restrict__ bias = (p == 0) ? bq : (p == 1) ? bk : bv;
  ushort_t* __restrict__ outp = (p == 0) ? qs : (p == 1) ? kvt : kvt + 128;
  const float scale = (p == 0) ? 0.25f : 1.0f;

  // ---- stage: W fp32 -> split -> LDS (hi and lo together) ----
#pragma unroll
  for (int jj = 0; jj < 8; jj++) {            // wave covers j = wave*8 + jj
    const int j = wave * 8 + jj, t = j >> 2, kt = j & 3;
    const float* wp = W + (size_t)(t * 16 + lm) * HID + kt * 32 + lq * 8;
    short8 bh, bl;
    split8p(wp, bh, bl);
    *(short8*)(lds_b + j * 1024 + l * 16) = bh;
    *(short8*)(lds_b + 32768 + j * 1024 + l * 16) = bl;
  }

  // --- A: load h rows and split to bf16 hi/lo (overlaps the staging above).
  int ar0 = m0 + lm;        if (ar0 >= n) ar0 = n - 1;
  int ar1 = m0 + 16 + lm;   if (ar1 >= n) ar1 = n - 1;
  const float* ap0 = h + (size_t)ar0 * HID + lq * 8;
  const float* ap1 = h + (size_t)ar1 * HID + lq * 8;
  short8 ah0[4], al0[4], ah1[4], al1[4];
#pragma unroll
  for (int kt = 0; kt < 4; kt++) {
    split8p(ap0 + kt * 32, ah0[kt], al0[kt]);
    split8p(ap1 + kt * 32, ah1[kt], al1[kt]);
  }

  __syncthreads();                             // fragments visible to all waves

  f32x4 acc[2][8];
#pragma unroll
  for (int f = 0; f < 2; f++)
#pragma unroll
    for (int t = 0; t < 8; t++) acc[f][t] = (f32x4){0.f, 0.f, 0.f, 0.f};

  // ---- hi phase (same accumulation order as r16: bit-identical) ----
#pragma unroll
  for (int kt = 0; kt < 4; kt++) {
#pragma unroll
    for (int t = 0; t < 8; t++) {
      short8 bh = *(const short8*)(lds_b + (t * 4 + kt) * 1024 + l * 16);
      acc[0][t] = __builtin_amdgcn_mfma_f32_16x16x32_bf16(ah0[kt], bh, acc[0][t], 0, 0, 0);
      acc[0][t] = __builtin_amdgcn_mfma_f32_16x16x32_bf16(al0[kt], bh, acc[0][t], 0, 0, 0);
      acc[1][t] = __builtin_amdgcn_mfma_f32_16x16x32_bf16(ah1[kt], bh, acc[1][t], 0, 0, 0);
      acc[1][t] = __builtin_amdgcn_mfma_f32_16x16x32_bf16(al1[kt], bh, acc[1][t], 0, 0, 0);
    }
  }
  // ---- lo phase ----
#pragma unroll
  for (int kt = 0; kt < 4; kt++) {
#pragma unroll
    for (int t = 0; t < 8; t++) {
      short8 bl = *(const short8*)(lds_b + 32768 + (t * 4 + kt) * 1024 + l * 16);
      acc[0][t] = __builtin_amdgcn_mfma_f32_16x16x32_bf16(ah0[kt], bl, acc[0][t], 0, 0, 0);
      acc[1][t] = __builtin_amdgcn_mfma_f32_16x16x32_bf16(ah1[kt], bl, acc[1][t], 0, 0, 0);
    }
  }
  __syncthreads();                             // all waves done reading B;
                                               // front region now dead

  // ---- epilogue: fragments -> repack (aliased over B[0,33.8K)) -> stores ----
  ushort_t* lo_ = (ushort_t*)lds_b + wave * 32 * OSTRIDE_LDS;
#pragma unroll
  for (int t = 0; t < 8; t++) {
    const int col = t * 16 + lm;
    const float bv_ = bias[col];
#pragma unroll
    for (int f = 0; f < 2; f++) {
#pragma unroll
      for (int r = 0; r < 4; r++) {
        lo_[(f * 16 + lq * 4 + r) * OSTRIDE_LDS + col] = f2bf((acc[f][t][r] + bv_) * scale);
      }
    }
  }
  asm volatile("s_waitcnt lgkmcnt(0)" ::: "memory");   // wave-local ordering
  __builtin_amdgcn_wave_barrier();

  const int rr = l >> 5;
  const int ch = l & 31;
#pragma unroll
  for (int it = 0; it < 16; it++) {
    const int rw = it * 2 + rr;                // row within wave, 0..31
    const int grow = m0 + rw;
    short4v val = *(short4v*)(lo_ + rw * OSTRIDE_LDS + ch * 4);
    if (grow < n) *(short4v*)(outp + (size_t)grow * 256 + ch * 4) = val;
  }
}

// ---------------- Phase 2: fused scores + softmax + aggregate ----------------
// One wave per row. K|V interleaved per node (512B block). At the compulsory
// random-gather byte wall (~54us) — do not touch.
__global__ __launch_bounds__(256) void attn_kernel(
    const int* __restrict__ col_ind,
    const ushort_t* __restrict__ qs, const ushort_t* __restrict__ kvt,
    float* __restrict__ out, int n) {
  __shared__ __align__(16) float lds_attn[4 * DEG * 8];  // [wave][edge][head]

  const int wv = threadIdx.x >> 6;
  const int l = threadIdx.x & 63;
  const int lm = l & 15;
  const int lq = l >> 4;

  int row = blockIdx.x * 4 + wv;
  if (row >= n) row = n - 1;
  const int eb = row * DEG;

  // this lane's A-operand edge (streaming: nt)
  const int cm = __builtin_nontemporal_load(col_ind + eb + lm);
  const ushort_t* kp = kvt + (size_t)cm * 256 + lq * 8;   // K half of node block
  const ushort_t* qp = qs + (size_t)row * 256;     // q embedded in out row

  short8 af[4];
  ushort_t qv[4];
#pragma unroll
  for (int kt = 0; kt < 4; kt++) {
    af[kt] = *(const short8*)(kp + kt * 32);       // K: cached (reused 16x)
    qv[kt] = (lm < 8) ? __builtin_nontemporal_load(qp + kt * 32 + lq * 8 + lm)
                      : (ushort_t)0;               // q: streaming, nt
  }

  uint32 vreg[DEG];
#pragma unroll
  for (int e = 0; e < DEG; e++) {
    const int c = col_ind[eb + e];                 // wave-uniform -> s_load
    vreg[e] = *(const uint32*)(kvt + (size_t)c * 256 + 128 + 2 * l);  // V half
  }

  f32x4 acc = (f32x4){0.f, 0.f, 0.f, 0.f};
#pragma unroll
  for (int kt = 0; kt < 4; kt++) {
    short8 bf;
#pragma unroll
    for (int j = 0; j < 8; j++) bf[j] = (lm == j) ? (short)qv[kt] : (short)0;
    acc = __builtin_amdgcn_mfma_f32_16x16x32_bf16(af[kt], bf, acc, 0, 0, 0);
  }

  float m = fmaxf(fmaxf(acc[0], acc[1]), fmaxf(acc[2], acc[3]));
  m = fmaxf(m, __shfl_xor(m, 16, 64));
  m = fmaxf(m, __shfl_xor(m, 32, 64));
  float e0 = __expf(acc[0] - m), e1 = __expf(acc[1] - m);
  float e2 = __expf(acc[2] - m), e3 = __expf(acc[3] - m);
  float s = e0 + e1 + e2 + e3;
  s += __shfl_xor(s, 16, 64);
  s += __shfl_xor(s, 32, 64);
  const float inv = 1.0f / s;

  float* ap = &lds_attn[wv * (DEG * 8)];
  if (lm < 8) {
    ap[(lq * 4 + 0) * 8 + lm] = e0 * inv;
    ap[(lq * 4 + 1) * 8 + lm] = e1 * inv;
    ap[(lq * 4 + 2) * 8 + lm] = e2 * inv;
    ap[(lq * 4 + 3) * 8 + lm] = e3 * inv;
  }
  asm volatile("s_waitcnt lgkmcnt(0)" ::: "memory");
  __builtin_amdgcn_wave_barrier();

  const int h0 = 2 * (l & 3);
  float o0 = 0.f, o1 = 0.f;
#pragma unroll
  for (int e = 0; e < DEG; e++) {
    const float2 at = *(const float2*)(ap + e * 8 + h0);
    o0 += at.x * bf2f((ushort_t)(vreg[e] & 0xffffu));
    o1 += at.y * bf2f((ushort_t)(vreg[e] >> 16));
  }

  f32x2 o;
  o[0] = o0; o[1] = o1;
  // out store: streaming, nt (overwrites consumed q)
  __builtin_nontemporal_store(o, (f32x2*)(out + (size_t)row * HID + 2 * l));
}

extern "C" void kernel_launch(void* const* d_in, const int* in_sizes, int n_in,
                              void* d_out, int out_size, void* d_ws, size_t ws_size,
                              hipStream_t stream) {
  const float* h  = (const float*)d_in[0];
  const float* Wq = (const float*)d_in[1];
  const float* bq = (const float*)d_in[2];
  const float* Wk = (const float*)d_in[3];
  const float* bk = (const float*)d_in[4];
  const float* Wv = (const float*)d_in[5];
  const float* bv = (const float*)d_in[6];
  // d_in[7] = row_ptr (fixed degree 16) — unused
  const int* col_ind = (const int*)d_in[8];
  // d_in[9] = num_heads (= 8) — hardcoded in layout math

  const int n = in_sizes[0] / HID;  // 50000

  // ws layout (~25.6 MB): interleaved K|V table (512B/node). q (bf16) lives
  // in the first 256 B of each row's 512 B fp32 out slot.
  ushort_t* kvt = (ushort_t*)d_ws;
  ushort_t* qs  = (ushort_t*)d_out;
  float* outf   = (float*)d_out;

  const int nb = (n + 127) / 128;   // 391 row tiles
  qkv_fused_kernel<<<3 * nb, 256, 0, stream>>>(
      h, Wq, bq, Wk, bk, Wv, bv, qs, kvt, n, nb);
  attn_kernel<<<(n + 3) / 4, 256, 0, stream>>>(col_ind, qs, kvt, outf, n);
}

// Round 9
// 172.006 us; speedup vs baseline: 1.0217x; 1.0217x over previous
//
#include <hip/hip_runtime.h>
#include <hip/hip_bf16.h>

// SparseMHA, fixed out-degree CSR graph attention. fp32 in/out.
// r17 -> r18: REVERT to r16 (best measured: 172.57us). Final state.
//
// Session ledger (9 rounds):
//  * attn (54.4us): compulsory random-gather byte wall. FETCH 179MB ==
//    8 XCDs x 86% unique-touch x 25.6MB K/V table. Falsified: request-rate
//    (r12), per-wave MLP (r10), L2 pollution/nt (r13), burst-length/KV-
//    interleave (r14). Byte floor at bf16; fp8 K/V numerically blocked.
//  * qkv (~43us): invariant across FIVE structures (r9 DMA 4-wave, r10/r11
//    pipelined dbuf, r15 single-wave, r16 VALU-staged fused, r17 grid-
//    unrolled). Bottom-up cycle model says ~15us; the uniform ~3x multiplier
//    across all structures + r15's all-pipes-at-7% signature is consistent
//    with DVFS-throttled clocks following ~75us of near-idle harness
//    re-poison memsets each iteration — not addressable from kernel source.
//  * ~75us fixed: harness reset() memsets inside the timed region.
//  Sum of floors ~= 172 == measured best. Roofline.

typedef unsigned short ushort_t;
typedef unsigned int uint32;
typedef short short8 __attribute__((ext_vector_type(8)));
typedef short short4v __attribute__((ext_vector_type(4)));
typedef float f32x4 __attribute__((ext_vector_type(4)));
typedef float f32x2 __attribute__((ext_vector_type(2)));

#define HID 128
#define DEG 16
#define OSTRIDE_LDS 132   // ushort row stride in LDS repack (bank-conflict-free)

__device__ __forceinline__ float bf2f(ushort_t u) {
  uint32 x = ((uint32)u) << 16;
  return __builtin_bit_cast(float, x);
}
__device__ __forceinline__ ushort_t f2bf(float f) {
  uint32 u = __builtin_bit_cast(uint32, f);
  u += 0x7fffu + ((u >> 16) & 1u);   // RNE
  return (ushort_t)(u >> 16);
}

// Packed split of 2 fp32 -> packed bf16 hi pair + lo pair (RNE, v_cvt_pk path).
__device__ __forceinline__ void split2(float x, float y, uint32& hi, uint32& lo) {
  __hip_bfloat162 h2 = __float22bfloat162_rn(float2{x, y});
  __builtin_memcpy(&hi, &h2, 4);
  float hx = __builtin_bit_cast(float, hi << 16);
  float hy = __builtin_bit_cast(float, hi & 0xffff0000u);
  __hip_bfloat162 l2 = __float22bfloat162_rn(float2{x - hx, y - hy});
  __builtin_memcpy(&lo, &l2, 4);
}

__device__ __forceinline__ void split8v(float4 a, float4 b, short8& hi, short8& lo) {
  uint32* hu = (uint32*)&hi;
  uint32* lu = (uint32*)&lo;
  split2(a.x, a.y, hu[0], lu[0]);
  split2(a.z, a.w, hu[1], lu[1]);
  split2(b.x, b.y, hu[2], lu[2]);
  split2(b.z, b.w, hu[3], lu[3]);
}

__device__ __forceinline__ void split8p(const float* __restrict__ p, short8& hi, short8& lo) {
  float4 a = *(const float4*)p;
  float4 b = *(const float4*)(p + 4);
  split8v(a, b, hi, lo);
}

// ---------------- Phase 1: fused W-split + Q+K+V projection ----------------
// One block = 128 rows (4 waves x 32 rows, 2 A-fragments each). Per
// projection: each wave loads its 8 W-fragments as fp32 (L2-hit), splits to
// bf16 hi/lo in VALU, ds_writes to hi[0,32K) / lo[32K,64K); ONE sync; 192
// MFMAs; sync; repack into the (dead) B region; stores; sync.
// B fragment slot j = t*4+kt (1KB each): lane l holds bytes j*1024 + l*16.
__global__ __launch_bounds__(256) void qkv_fused_kernel(
    const float* __restrict__ h,
    const float* __restrict__ Wq, const float* __restrict__ bq,
    const float* __restrict__ Wk, const float* __restrict__ bk,
    const float* __restrict__ Wv, const float* __restrict__ bv,
    ushort_t* __restrict__ qs, ushort_t* __restrict__ kvt,
    int n) {
  __shared__ __align__(16) char lds_b[64 * 1024];   // hi | lo fragments; front
                                                    // 33.8KB reused as repack
  const int wave = threadIdx.x >> 6;
  const int l = threadIdx.x & 63;
  const int lm = l & 15;
  const int lq = l >> 4;
  const int m0 = blockIdx.x * 128 + wave * 32;

  // --- A: load h rows and split to bf16 hi/lo ONCE; reused by all 3 projections.
  int ar0 = m0 + lm;        if (ar0 >= n) ar0 = n - 1;
  int ar1 = m0 + 16 + lm;   if (ar1 >= n) ar1 = n - 1;
  const float* ap0 = h + (size_t)ar0 * HID + lq * 8;
  const float* ap1 = h + (size_t)ar1 * HID + lq * 8;
  short8 ah0[4], al0[4], ah1[4], al1[4];
#pragma unroll
  for (int kt = 0; kt < 4; kt++) {
    split8p(ap0 + kt * 32, ah0[kt], al0[kt]);
    split8p(ap1 + kt * 32, ah1[kt], al1[kt]);
  }

#pragma unroll 1
  for (int p = 0; p < 3; p++) {
    const float* __restrict__ W = (p == 0) ? Wq : (p == 1) ? Wk : Wv;
    const float* __restrict__ bias = (p == 0) ? bq : (p == 1) ? bk : bv;
    ushort_t* __restrict__ outp = (p == 0) ? qs : (p == 1) ? kvt : kvt + 128;
    const float scale = (p == 0) ? 0.25f : 1.0f;

    // ---- stage: W fp32 -> split -> LDS (hi and lo together) ----
#pragma unroll
    for (int jj = 0; jj < 8; jj++) {            // wave covers j = wave*8 + jj
      const int j = wave * 8 + jj, t = j >> 2, kt = j & 3;
      const float* wp = W + (size_t)(t * 16 + lm) * HID + kt * 32 + lq * 8;
      short8 bh, bl;
      split8p(wp, bh, bl);
      *(short8*)(lds_b + j * 1024 + l * 16) = bh;
      *(short8*)(lds_b + 32768 + j * 1024 + l * 16) = bl;
    }
    __syncthreads();                             // fragments visible to all waves

    f32x4 acc[2][8];
#pragma unroll
    for (int f = 0; f < 2; f++)
#pragma unroll
      for (int t = 0; t < 8; t++) acc[f][t] = (f32x4){0.f, 0.f, 0.f, 0.f};

    // ---- hi phase ----
#pragma unroll
    for (int kt = 0; kt < 4; kt++) {
#pragma unroll
      for (int t = 0; t < 8; t++) {
        short8 bh = *(const short8*)(lds_b + (t * 4 + kt) * 1024 + l * 16);
        acc[0][t] = __builtin_amdgcn_mfma_f32_16x16x32_bf16(ah0[kt], bh, acc[0][t], 0, 0, 0);
        acc[0][t] = __builtin_amdgcn_mfma_f32_16x16x32_bf16(al0[kt], bh, acc[0][t], 0, 0, 0);
        acc[1][t] = __builtin_amdgcn_mfma_f32_16x16x32_bf16(ah1[kt], bh, acc[1][t], 0, 0, 0);
        acc[1][t] = __builtin_amdgcn_mfma_f32_16x16x32_bf16(al1[kt], bh, acc[1][t], 0, 0, 0);
      }
    }
    // ---- lo phase ----
#pragma unroll
    for (int kt = 0; kt < 4; kt++) {
#pragma unroll
      for (int t = 0; t < 8; t++) {
        short8 bl = *(const short8*)(lds_b + 32768 + (t * 4 + kt) * 1024 + l * 16);
        acc[0][t] = __builtin_amdgcn_mfma_f32_16x16x32_bf16(ah0[kt], bl, acc[0][t], 0, 0, 0);
        acc[1][t] = __builtin_amdgcn_mfma_f32_16x16x32_bf16(ah1[kt], bl, acc[1][t], 0, 0, 0);
      }
    }
    __syncthreads();                             // all waves done reading B;
                                                 // front region now dead

    // ---- epilogue: fragments -> repack (aliased over B[0,33.8K)) -> stores ----
    ushort_t* lo_ = (ushort_t*)lds_b + wave * 32 * OSTRIDE_LDS;
#pragma unroll
    for (int t = 0; t < 8; t++) {
      const int col = t * 16 + lm;
      const float bv_ = bias[col];
#pragma unroll
      for (int f = 0; f < 2; f++) {
#pragma unroll
        for (int r = 0; r < 4; r++) {
          lo_[(f * 16 + lq * 4 + r) * OSTRIDE_LDS + col] = f2bf((acc[f][t][r] + bv_) * scale);
        }
      }
    }
    asm volatile("s_waitcnt lgkmcnt(0)" ::: "memory");   // wave-local ordering
    __builtin_amdgcn_wave_barrier();

    const int rr = l >> 5;
    const int ch = l & 31;
#pragma unroll
    for (int it = 0; it < 16; it++) {
      const int rw = it * 2 + rr;                // row within wave, 0..31
      const int grow = m0 + rw;
      short4v val = *(short4v*)(lo_ + rw * OSTRIDE_LDS + ch * 4);
      if (grow < n) *(short4v*)(outp + (size_t)grow * 256 + ch * 4) = val;
    }
    __syncthreads();                             // repack reads done before next
                                                 // projection's staging writes
  }
}

// ---------------- Phase 2: fused scores + softmax + aggregate ----------------
// One wave per row. K|V interleaved per node (512B block). At the compulsory
// random-gather byte wall (~54us) — do not touch.
__global__ __launch_bounds__(256) void attn_kernel(
    const int* __restrict__ col_ind,
    const ushort_t* __restrict__ qs, const ushort_t* __restrict__ kvt,
    float* __restrict__ out, int n) {
  __shared__ __align__(16) float lds_attn[4 * DEG * 8];  // [wave][edge][head]

  const int wv = threadIdx.x >> 6;
  const int l = threadIdx.x & 63;
  const int lm = l & 15;
  const int lq = l >> 4;

  int row = blockIdx.x * 4 + wv;
  if (row >= n) row = n - 1;
  const int eb = row * DEG;

  // this lane's A-operand edge (streaming: nt)
  const int cm = __builtin_nontemporal_load(col_ind + eb + lm);
  const ushort_t* kp = kvt + (size_t)cm * 256 + lq * 8;   // K half of node block
  const ushort_t* qp = qs + (size_t)row * 256;     // q embedded in out row

  short8 af[4];
  ushort_t qv[4];
#pragma unroll
  for (int kt = 0; kt < 4; kt++) {
    af[kt] = *(const short8*)(kp + kt * 32);       // K: cached (reused 16x)
    qv[kt] = (lm < 8) ? __builtin_nontemporal_load(qp + kt * 32 + lq * 8 + lm)
                      : (ushort_t)0;               // q: streaming, nt
  }

  uint32 vreg[DEG];
#pragma unroll
  for (int e = 0; e < DEG; e++) {
    const int c = col_ind[eb + e];                 // wave-uniform -> s_load
    vreg[e] = *(const uint32*)(kvt + (size_t)c * 256 + 128 + 2 * l);  // V half
  }

  f32x4 acc = (f32x4){0.f, 0.f, 0.f, 0.f};
#pragma unroll
  for (int kt = 0; kt < 4; kt++) {
    short8 bf;
#pragma unroll
    for (int j = 0; j < 8; j++) bf[j] = (lm == j) ? (short)qv[kt] : (short)0;
    acc = __builtin_amdgcn_mfma_f32_16x16x32_bf16(af[kt], bf, acc, 0, 0, 0);
  }

  float m = fmaxf(fmaxf(acc[0], acc[1]), fmaxf(acc[2], acc[3]));
  m = fmaxf(m, __shfl_xor(m, 16, 64));
  m = fmaxf(m, __shfl_xor(m, 32, 64));
  float e0 = __expf(acc[0] - m), e1 = __expf(acc[1] - m);
  float e2 = __expf(acc[2] - m), e3 = __expf(acc[3] - m);
  float s = e0 + e1 + e2 + e3;
  s += __shfl_xor(s, 16, 64);
  s += __shfl_xor(s, 32, 64);
  const float inv = 1.0f / s;

  float* ap = &lds_attn[wv * (DEG * 8)];
  if (lm < 8) {
    ap[(lq * 4 + 0) * 8 + lm] = e0 * inv;
    ap[(lq * 4 + 1) * 8 + lm] = e1 * inv;
    ap[(lq * 4 + 2) * 8 + lm] = e2 * inv;
    ap[(lq * 4 + 3) * 8 + lm] = e3 * inv;
  }
  asm volatile("s_waitcnt lgkmcnt(0)" ::: "memory");
  __builtin_amdgcn_wave_barrier();

  const int h0 = 2 * (l & 3);
  float o0 = 0.f, o1 = 0.f;
#pragma unroll
  for (int e = 0; e < DEG; e++) {
    const float2 at = *(const float2*)(ap + e * 8 + h0);
    o0 += at.x * bf2f((ushort_t)(vreg[e] & 0xffffu));
    o1 += at.y * bf2f((ushort_t)(vreg[e] >> 16));
  }

  f32x2 o;
  o[0] = o0; o[1] = o1;
  // out store: streaming, nt (overwrites consumed q)
  __builtin_nontemporal_store(o, (f32x2*)(out + (size_t)row * HID + 2 * l));
}

extern "C" void kernel_launch(void* const* d_in, const int* in_sizes, int n_in,
                              void* d_out, int out_size, void* d_ws, size_t ws_size,
                              hipStream_t stream) {
  const float* h  = (const float*)d_in[0];
  const float* Wq = (const float*)d_in[1];
  const float* bq = (const float*)d_in[2];
  const float* Wk = (const float*)d_in[3];
  const float* bk = (const float*)d_in[4];
  const float* Wv = (const float*)d_in[5];
  const float* bv = (const float*)d_in[6];
  // d_in[7] = row_ptr (fixed degree 16) — unused
  const int* col_ind = (const int*)d_in[8];
  // d_in[9] = num_heads (= 8) — hardcoded in layout math

  const int n = in_sizes[0] / HID;  // 50000

  // ws layout (~25.6 MB): interleaved K|V table (512B/node). q (bf16) lives
  // in the first 256 B of each row's 512 B fp32 out slot.
  ushort_t* kvt = (ushort_t*)d_ws;
  ushort_t* qs  = (ushort_t*)d_out;
  float* outf   = (float*)d_out;

  qkv_fused_kernel<<<(n + 127) / 128, 256, 0, stream>>>(
      h, Wq, bq, Wk, bk, Wv, bv, qs, kvt, n);
  attn_kernel<<<(n + 3) / 4, 256, 0, stream>>>(col_ind, qs, kvt, outf, n);
}